// Round 11
// baseline (1249.395 us; speedup 1.0000x reference)
//
#include <hip/hip_runtime.h>
#include <hip/hip_bf16.h>
#include <math.h>

#define NLVL 8
#define LOG2T 19
#define TSZ (1u << LOG2T)

typedef float f32x2 __attribute__((ext_vector_type(2)));

struct Scales { float s[NLVL]; };

static __device__ __forceinline__ unsigned short f2bf(float f) {
    unsigned u = __builtin_bit_cast(unsigned, f);
    u += 0x7fffu + ((u >> 16) & 1u);   // round-to-nearest-even
    return (unsigned short)(u >> 16);
}
static __device__ __forceinline__ float bfbits2f(unsigned hi16) {
    return __builtin_bit_cast(float, hi16);
}

// Agent-scope (device) load: emits global_load_dwordx2 with sc1 -> bypasses L1.
// Tests the "L1 line-fill path is the gather bottleneck" theory.
static __device__ __forceinline__ f32x2 ld_bypass(const f32x2* p) {
    unsigned long long raw = __hip_atomic_load(
        reinterpret_cast<const unsigned long long*>(p),
        __ATOMIC_RELAXED, __HIP_MEMORY_SCOPE_AGENT);
    return __builtin_bit_cast(f32x2, raw);
}

// ---------------- Level-parallel encode: level = blockIdx.x & 7 ----------------
// r3-verified: XCD partitioning keeps each level's 4 MB table in one XCD's L2
// (FETCH 5 GB -> 0.13 GB). This round: identical structure, L1-bypassing gathers.
__global__ __launch_bounds__(256) void encode_kernel(
    const float* __restrict__ x,      // [N,3]
    const float* __restrict__ table,  // [L,T,2]
    unsigned* __restrict__ encb,      // [L][N] packed bf16x2
    int N, Scales sc)
{
    const int lvl = blockIdx.x & 7;
    const int i = (blockIdx.x >> 3) * blockDim.x + threadIdx.x;
    if (i >= N) return;

    float xx = __builtin_nontemporal_load(x + 3 * i + 0);
    float yy = __builtin_nontemporal_load(x + 3 * i + 1);
    float zz = __builtin_nontemporal_load(x + 3 * i + 2);
    float px = (xx + 1.0f) * 0.5f;
    float py = (yy + 1.0f) * 0.5f;
    float pz = (zz + 1.0f) * 0.5f;

    const float s = sc.s[lvl];
    float fx = fmaf(px, s, 0.5f);
    float fy = fmaf(py, s, 0.5f);
    float fz = fmaf(pz, s, 0.5f);
    float bx = floorf(fx), by = floorf(fy), bz = floorf(fz);
    float wx = fx - bx, wy = fy - by, wz = fz - bz;
    unsigned cx = (unsigned)bx, cy = (unsigned)by, cz = (unsigned)bz;

    unsigned hy0 = cy * 2654435761u;
    unsigned hy1 = hy0 + 2654435761u;
    unsigned hz0 = cz * 805459861u;
    unsigned hz1 = hz0 + 805459861u;
    unsigned cx1 = cx + 1u;
    const unsigned m = TSZ - 1u;
    const f32x2* tl = reinterpret_cast<const f32x2*>(table) + (size_t)lvl * TSZ;

    f32x2 f000 = ld_bypass(tl + ((cx  ^ hy0 ^ hz0) & m));
    f32x2 f100 = ld_bypass(tl + ((cx1 ^ hy0 ^ hz0) & m));
    f32x2 f010 = ld_bypass(tl + ((cx  ^ hy1 ^ hz0) & m));
    f32x2 f110 = ld_bypass(tl + ((cx1 ^ hy1 ^ hz0) & m));
    f32x2 f001 = ld_bypass(tl + ((cx  ^ hy0 ^ hz1) & m));
    f32x2 f101 = ld_bypass(tl + ((cx1 ^ hy0 ^ hz1) & m));
    f32x2 f011 = ld_bypass(tl + ((cx  ^ hy1 ^ hz1) & m));
    f32x2 f111 = ld_bypass(tl + ((cx1 ^ hy1 ^ hz1) & m));

    float wx0 = 1.0f - wx, wy0 = 1.0f - wy, wz0 = 1.0f - wz;
    float w00 = wx0 * wy0, w10 = wx * wy0, w01 = wx0 * wy, w11 = wx * wy;
    float a000 = w00 * wz0, a100 = w10 * wz0, a010 = w01 * wz0, a110 = w11 * wz0;
    float a001 = w00 * wz,  a101 = w10 * wz,  a011 = w01 * wz,  a111 = w11 * wz;

    float e0 = fmaf(f000.x, a000,
               fmaf(f100.x, a100,
               fmaf(f010.x, a010,
               fmaf(f110.x, a110,
               fmaf(f001.x, a001,
               fmaf(f101.x, a101,
               fmaf(f011.x, a011, f111.x * a111)))))));
    float e1 = fmaf(f000.y, a000,
               fmaf(f100.y, a100,
               fmaf(f010.y, a010,
               fmaf(f110.y, a110,
               fmaf(f001.y, a001,
               fmaf(f101.y, a101,
               fmaf(f011.y, a011, f111.y * a111)))))));

    unsigned pk = ((unsigned)f2bf(e1) << 16) | (unsigned)f2bf(e0);
    __builtin_nontemporal_store(pk, encb + (size_t)lvl * N + i);
}

// ---------------- MLP pass: 16 -> 32 relu -> 1 sigmoid ----------------
__global__ __launch_bounds__(256) void mlp_kernel(
    const unsigned* __restrict__ encb,  // [L][N] packed bf16x2
    const float* __restrict__ W1,       // [16,32]
    const float* __restrict__ b1,       // [32]
    const float* __restrict__ W2,       // [32]
    const float* __restrict__ b2,       // [1]
    float* __restrict__ out, int N)
{
    int i = blockIdx.x * blockDim.x + threadIdx.x;
    if (i >= N) return;

    float enc[16];
    #pragma unroll
    for (int l = 0; l < NLVL; ++l) {
        unsigned pk = __builtin_nontemporal_load(encb + (size_t)l * N + i);
        enc[2 * l + 0] = bfbits2f(pk << 16);
        enc[2 * l + 1] = bfbits2f(pk & 0xffff0000u);
    }

    float h[32];
    #pragma unroll
    for (int j = 0; j < 32; ++j) h[j] = b1[j];
    #pragma unroll
    for (int k = 0; k < 16; ++k) {
        float e = enc[k];
        #pragma unroll
        for (int j = 0; j < 32; ++j)
            h[j] = fmaf(e, W1[k * 32 + j], h[j]);
    }
    float z = b2[0];
    #pragma unroll
    for (int j = 0; j < 32; ++j)
        z = fmaf(fmaxf(h[j], 0.0f), W2[j], z);

    out[i] = 1.0f / (1.0f + __expf(-z));
}

// ---------------- Fallback: fully fused (ws too small) ----------------
__global__ __launch_bounds__(256) void fused_kernel(
    const float* __restrict__ x, const float* __restrict__ table,
    const float* __restrict__ W1, const float* __restrict__ b1,
    const float* __restrict__ W2, const float* __restrict__ b2,
    float* __restrict__ out, int N, Scales sc)
{
    int i = blockIdx.x * blockDim.x + threadIdx.x;
    if (i >= N) return;
    float px = (x[3 * i + 0] + 1.0f) * 0.5f;
    float py = (x[3 * i + 1] + 1.0f) * 0.5f;
    float pz = (x[3 * i + 2] + 1.0f) * 0.5f;
    float enc[16];
    #pragma unroll
    for (int l = 0; l < NLVL; ++l) {
        const float s = sc.s[l];
        float fx = fmaf(px, s, 0.5f), fy = fmaf(py, s, 0.5f), fz = fmaf(pz, s, 0.5f);
        float bx = floorf(fx), by = floorf(fy), bz = floorf(fz);
        float wx = fx - bx, wy = fy - by, wz = fz - bz;
        unsigned cx = (unsigned)bx, cy = (unsigned)by, cz = (unsigned)bz;
        unsigned hy0 = cy * 2654435761u, hy1 = hy0 + 2654435761u;
        unsigned hz0 = cz * 805459861u, hz1 = hz0 + 805459861u;
        unsigned cx1 = cx + 1u;
        const unsigned m = TSZ - 1u;
        const f32x2* tl = reinterpret_cast<const f32x2*>(table) + (size_t)l * TSZ;
        f32x2 f000 = tl[(cx ^ hy0 ^ hz0) & m], f100 = tl[(cx1 ^ hy0 ^ hz0) & m];
        f32x2 f010 = tl[(cx ^ hy1 ^ hz0) & m], f110 = tl[(cx1 ^ hy1 ^ hz0) & m];
        f32x2 f001 = tl[(cx ^ hy0 ^ hz1) & m], f101 = tl[(cx1 ^ hy0 ^ hz1) & m];
        f32x2 f011 = tl[(cx ^ hy1 ^ hz1) & m], f111 = tl[(cx1 ^ hy1 ^ hz1) & m];
        float wx0 = 1.0f - wx, wy0 = 1.0f - wy, wz0 = 1.0f - wz;
        float w00 = wx0 * wy0, w10 = wx * wy0, w01 = wx0 * wy, w11 = wx * wy;
        float a000 = w00 * wz0, a100 = w10 * wz0, a010 = w01 * wz0, a110 = w11 * wz0;
        float a001 = w00 * wz, a101 = w10 * wz, a011 = w01 * wz, a111 = w11 * wz;
        enc[2*l+0] = fmaf(f000.x,a000, fmaf(f100.x,a100, fmaf(f010.x,a010, fmaf(f110.x,a110,
                     fmaf(f001.x,a001, fmaf(f101.x,a101, fmaf(f011.x,a011, f111.x*a111)))))));
        enc[2*l+1] = fmaf(f000.y,a000, fmaf(f100.y,a100, fmaf(f010.y,a010, fmaf(f110.y,a110,
                     fmaf(f001.y,a001, fmaf(f101.y,a101, fmaf(f011.y,a011, f111.y*a111)))))));
    }
    float h[32];
    #pragma unroll
    for (int j = 0; j < 32; ++j) h[j] = b1[j];
    #pragma unroll
    for (int k = 0; k < 16; ++k) {
        float e = enc[k];
        #pragma unroll
        for (int j = 0; j < 32; ++j) h[j] = fmaf(e, W1[k * 32 + j], h[j]);
    }
    float z = b2[0];
    #pragma unroll
    for (int j = 0; j < 32; ++j) z = fmaf(fmaxf(h[j], 0.0f), W2[j], z);
    out[i] = 1.0f / (1.0f + __expf(-z));
}

extern "C" void kernel_launch(void* const* d_in, const int* in_sizes, int n_in,
                              void* d_out, int out_size, void* d_ws, size_t ws_size,
                              hipStream_t stream) {
    const float* x     = (const float*)d_in[0];
    const float* table = (const float*)d_in[1];
    const float* W1    = (const float*)d_in[2];
    const float* b1    = (const float*)d_in[3];
    const float* W2    = (const float*)d_in[4];
    const float* b2    = (const float*)d_in[5];
    float* out = (float*)d_out;

    int N = in_sizes[0] / 3;

    Scales sc;
    double B = exp(log(2048.0 / 32.0) / 7.0);
    for (int l = 0; l < NLVL; ++l)
        sc.s[l] = (float)(32.0 * pow(B, (double)l) - 1.0);

    const int block = 256;
    const int chunks = (N + block - 1) / block;
    size_t need = (size_t)NLVL * (size_t)N * sizeof(unsigned);

    if (ws_size >= need) {
        unsigned* encb = (unsigned*)d_ws;
        encode_kernel<<<chunks * NLVL, block, 0, stream>>>(x, table, encb, N, sc);
        mlp_kernel<<<chunks, block, 0, stream>>>(encb, W1, b1, W2, b2, out, N);
    } else {
        fused_kernel<<<chunks, block, 0, stream>>>(x, table, W1, b1, W2, b2, out, N, sc);
    }
}

// Round 12
// 955.690 us; speedup vs baseline: 1.3073x; 1.3073x over previous
//
#include <hip/hip_runtime.h>
#include <hip/hip_bf16.h>
#include <math.h>

#define NLVL 8
#define LOG2T 19
#define TSZ (1u << LOG2T)

typedef float f32x2 __attribute__((ext_vector_type(2)));

struct Scales { float s[NLVL]; };

static __device__ __forceinline__ unsigned short f2bf(float f) {
    unsigned u = __builtin_bit_cast(unsigned, f);
    u += 0x7fffu + ((u >> 16) & 1u);   // round-to-nearest-even
    return (unsigned short)(u >> 16);
}
static __device__ __forceinline__ float bfbits2f(unsigned hi16) {
    return __builtin_bit_cast(float, hi16);
}

// -------- Persistent level-parallel encode: level = blockIdx.x & 7 ----------
// r3-verified: XCD partitioning keeps each level's 4 MB table L2-resident.
// This round: persistent grid-stride blocks (2048 = 8/CU x 256 CU) pin
// occupancy at max for the whole kernel (r3 measured only 77%) and amortize
// per-point setup. Per-thread gather structure identical to r3 (known-good).
__global__ __launch_bounds__(256) void encode_kernel(
    const float* __restrict__ x,      // [N,3]
    const float* __restrict__ table,  // [L,T,2]
    unsigned* __restrict__ encb,      // [L][N] packed bf16x2
    int N, Scales sc)
{
    const int lvl = blockIdx.x & 7;
    const int blk_in_lvl = blockIdx.x >> 3;          // 0..255
    const int nblk_lvl = gridDim.x >> 3;             // 256
    const int stride = nblk_lvl * blockDim.x;        // 65536

    const float s = sc.s[lvl];
    const unsigned m = TSZ - 1u;
    const f32x2* tl = reinterpret_cast<const f32x2*>(table) + (size_t)lvl * TSZ;
    unsigned* eb = encb + (size_t)lvl * N;

    for (int i = blk_in_lvl * blockDim.x + threadIdx.x; i < N; i += stride) {
        float xx = __builtin_nontemporal_load(x + 3 * i + 0);
        float yy = __builtin_nontemporal_load(x + 3 * i + 1);
        float zz = __builtin_nontemporal_load(x + 3 * i + 2);
        float px = (xx + 1.0f) * 0.5f;
        float py = (yy + 1.0f) * 0.5f;
        float pz = (zz + 1.0f) * 0.5f;

        float fx = fmaf(px, s, 0.5f);
        float fy = fmaf(py, s, 0.5f);
        float fz = fmaf(pz, s, 0.5f);
        float bx = floorf(fx), by = floorf(fy), bz = floorf(fz);
        float wx = fx - bx, wy = fy - by, wz = fz - bz;
        unsigned cx = (unsigned)bx, cy = (unsigned)by, cz = (unsigned)bz;

        unsigned hy0 = cy * 2654435761u;
        unsigned hy1 = hy0 + 2654435761u;
        unsigned hz0 = cz * 805459861u;
        unsigned hz1 = hz0 + 805459861u;
        unsigned cx1 = cx + 1u;

        f32x2 f000 = tl[(cx  ^ hy0 ^ hz0) & m];
        f32x2 f100 = tl[(cx1 ^ hy0 ^ hz0) & m];
        f32x2 f010 = tl[(cx  ^ hy1 ^ hz0) & m];
        f32x2 f110 = tl[(cx1 ^ hy1 ^ hz0) & m];
        f32x2 f001 = tl[(cx  ^ hy0 ^ hz1) & m];
        f32x2 f101 = tl[(cx1 ^ hy0 ^ hz1) & m];
        f32x2 f011 = tl[(cx  ^ hy1 ^ hz1) & m];
        f32x2 f111 = tl[(cx1 ^ hy1 ^ hz1) & m];

        float wx0 = 1.0f - wx, wy0 = 1.0f - wy, wz0 = 1.0f - wz;
        float w00 = wx0 * wy0, w10 = wx * wy0, w01 = wx0 * wy, w11 = wx * wy;
        float a000 = w00 * wz0, a100 = w10 * wz0, a010 = w01 * wz0, a110 = w11 * wz0;
        float a001 = w00 * wz,  a101 = w10 * wz,  a011 = w01 * wz,  a111 = w11 * wz;

        float e0 = fmaf(f000.x, a000,
                   fmaf(f100.x, a100,
                   fmaf(f010.x, a010,
                   fmaf(f110.x, a110,
                   fmaf(f001.x, a001,
                   fmaf(f101.x, a101,
                   fmaf(f011.x, a011, f111.x * a111)))))));
        float e1 = fmaf(f000.y, a000,
                   fmaf(f100.y, a100,
                   fmaf(f010.y, a010,
                   fmaf(f110.y, a110,
                   fmaf(f001.y, a001,
                   fmaf(f101.y, a101,
                   fmaf(f011.y, a011, f111.y * a111)))))));

        unsigned pk = ((unsigned)f2bf(e1) << 16) | (unsigned)f2bf(e0);
        __builtin_nontemporal_store(pk, eb + i);
    }
}

// ---------------- MLP pass: 16 -> 32 relu -> 1 sigmoid (persistent) ----------
__global__ __launch_bounds__(256) void mlp_kernel(
    const unsigned* __restrict__ encb,  // [L][N] packed bf16x2
    const float* __restrict__ W1,       // [16,32]
    const float* __restrict__ b1,       // [32]
    const float* __restrict__ W2,       // [32]
    const float* __restrict__ b2,       // [1]
    float* __restrict__ out, int N)
{
    const int stride = gridDim.x * blockDim.x;
    for (int i = blockIdx.x * blockDim.x + threadIdx.x; i < N; i += stride) {
        float enc[16];
        #pragma unroll
        for (int l = 0; l < NLVL; ++l) {
            unsigned pk = __builtin_nontemporal_load(encb + (size_t)l * N + i);
            enc[2 * l + 0] = bfbits2f(pk << 16);
            enc[2 * l + 1] = bfbits2f(pk & 0xffff0000u);
        }

        float h[32];
        #pragma unroll
        for (int j = 0; j < 32; ++j) h[j] = b1[j];
        #pragma unroll
        for (int k = 0; k < 16; ++k) {
            float e = enc[k];
            #pragma unroll
            for (int j = 0; j < 32; ++j)
                h[j] = fmaf(e, W1[k * 32 + j], h[j]);
        }
        float z = b2[0];
        #pragma unroll
        for (int j = 0; j < 32; ++j)
            z = fmaf(fmaxf(h[j], 0.0f), W2[j], z);

        out[i] = 1.0f / (1.0f + __expf(-z));
    }
}

// ---------------- Fallback: fully fused (ws too small) ----------------
__global__ __launch_bounds__(256) void fused_kernel(
    const float* __restrict__ x, const float* __restrict__ table,
    const float* __restrict__ W1, const float* __restrict__ b1,
    const float* __restrict__ W2, const float* __restrict__ b2,
    float* __restrict__ out, int N, Scales sc)
{
    int i = blockIdx.x * blockDim.x + threadIdx.x;
    if (i >= N) return;
    float px = (x[3 * i + 0] + 1.0f) * 0.5f;
    float py = (x[3 * i + 1] + 1.0f) * 0.5f;
    float pz = (x[3 * i + 2] + 1.0f) * 0.5f;
    float enc[16];
    #pragma unroll
    for (int l = 0; l < NLVL; ++l) {
        const float s = sc.s[l];
        float fx = fmaf(px, s, 0.5f), fy = fmaf(py, s, 0.5f), fz = fmaf(pz, s, 0.5f);
        float bx = floorf(fx), by = floorf(fy), bz = floorf(fz);
        float wx = fx - bx, wy = fy - by, wz = fz - bz;
        unsigned cx = (unsigned)bx, cy = (unsigned)by, cz = (unsigned)bz;
        unsigned hy0 = cy * 2654435761u, hy1 = hy0 + 2654435761u;
        unsigned hz0 = cz * 805459861u, hz1 = hz0 + 805459861u;
        unsigned cx1 = cx + 1u;
        const unsigned m = TSZ - 1u;
        const f32x2* tl = reinterpret_cast<const f32x2*>(table) + (size_t)l * TSZ;
        f32x2 f000 = tl[(cx ^ hy0 ^ hz0) & m], f100 = tl[(cx1 ^ hy0 ^ hz0) & m];
        f32x2 f010 = tl[(cx ^ hy1 ^ hz0) & m], f110 = tl[(cx1 ^ hy1 ^ hz0) & m];
        f32x2 f001 = tl[(cx ^ hy0 ^ hz1) & m], f101 = tl[(cx1 ^ hy0 ^ hz1) & m];
        f32x2 f011 = tl[(cx ^ hy1 ^ hz1) & m], f111 = tl[(cx1 ^ hy1 ^ hz1) & m];
        float wx0 = 1.0f - wx, wy0 = 1.0f - wy, wz0 = 1.0f - wz;
        float w00 = wx0 * wy0, w10 = wx * wy0, w01 = wx0 * wy, w11 = wx * wy;
        float a000 = w00 * wz0, a100 = w10 * wz0, a010 = w01 * wz0, a110 = w11 * wz0;
        float a001 = w00 * wz, a101 = w10 * wz, a011 = w01 * wz, a111 = w11 * wz;
        enc[2*l+0] = fmaf(f000.x,a000, fmaf(f100.x,a100, fmaf(f010.x,a010, fmaf(f110.x,a110,
                     fmaf(f001.x,a001, fmaf(f101.x,a101, fmaf(f011.x,a011, f111.x*a111)))))));
        enc[2*l+1] = fmaf(f000.y,a000, fmaf(f100.y,a100, fmaf(f010.y,a010, fmaf(f110.y,a110,
                     fmaf(f001.y,a001, fmaf(f101.y,a101, fmaf(f011.y,a011, f111.y*a111)))))));
    }
    float h[32];
    #pragma unroll
    for (int j = 0; j < 32; ++j) h[j] = b1[j];
    #pragma unroll
    for (int k = 0; k < 16; ++k) {
        float e = enc[k];
        #pragma unroll
        for (int j = 0; j < 32; ++j) h[j] = fmaf(e, W1[k * 32 + j], h[j]);
    }
    float z = b2[0];
    #pragma unroll
    for (int j = 0; j < 32; ++j) z = fmaf(fmaxf(h[j], 0.0f), W2[j], z);
    out[i] = 1.0f / (1.0f + __expf(-z));
}

extern "C" void kernel_launch(void* const* d_in, const int* in_sizes, int n_in,
                              void* d_out, int out_size, void* d_ws, size_t ws_size,
                              hipStream_t stream) {
    const float* x     = (const float*)d_in[0];
    const float* table = (const float*)d_in[1];
    const float* W1    = (const float*)d_in[2];
    const float* b1    = (const float*)d_in[3];
    const float* W2    = (const float*)d_in[4];
    const float* b2    = (const float*)d_in[5];
    float* out = (float*)d_out;

    int N = in_sizes[0] / 3;

    Scales sc;
    double B = exp(log(2048.0 / 32.0) / 7.0);
    for (int l = 0; l < NLVL; ++l)
        sc.s[l] = (float)(32.0 * pow(B, (double)l) - 1.0);

    const int block = 256;
    size_t need = (size_t)NLVL * (size_t)N * sizeof(unsigned);

    if (ws_size >= need) {
        unsigned* encb = (unsigned*)d_ws;
        // persistent: 8 blocks/CU x 256 CUs; level = blockIdx & 7 (XCD id)
        encode_kernel<<<2048, block, 0, stream>>>(x, table, encb, N, sc);
        mlp_kernel<<<2048, block, 0, stream>>>(encb, W1, b1, W2, b2, out, N);
    } else {
        int chunks = (N + block - 1) / block;
        fused_kernel<<<chunks, block, 0, stream>>>(x, table, W1, b1, W2, b2, out, N, sc);
    }
}

// Round 13
// 830.523 us; speedup vs baseline: 1.5043x; 1.1507x over previous
//
#include <hip/hip_runtime.h>
#include <hip/hip_bf16.h>
#include <math.h>

#define NLVL 8
#define LOG2T 19
#define TSZ (1u << LOG2T)

typedef float f32x2 __attribute__((ext_vector_type(2)));

struct Scales { float s[NLVL]; };

static __device__ __forceinline__ unsigned short f2bf(float f) {
    unsigned u = __builtin_bit_cast(unsigned, f);
    u += 0x7fffu + ((u >> 16) & 1u);   // round-to-nearest-even
    return (unsigned short)(u >> 16);
}
static __device__ __forceinline__ float bfbits2f(unsigned hi16) {
    return __builtin_bit_cast(float, hi16);
}

// ---------------- Level-parallel encode: level = blockIdx.x & 7 ----------------
// r3-verified optimum: XCD partitioning keeps each level's 4 MB table resident
// in one XCD's L2 (FETCH 5 GB -> 0.13 GB). Encode is bound by per-XCD L2
// random-request throughput (~16 req/cyc/XCD model ~= 870 us; measured 770 us).
// 7 structural variants (2pt/thread, corner pairing, fp16 table, sched pins,
// L1 bypass, persistent grid) ALL regressed vs this schedule.
__global__ __launch_bounds__(256) void encode_kernel(
    const float* __restrict__ x,      // [N,3]
    const float* __restrict__ table,  // [L,T,2]
    unsigned* __restrict__ encb,      // [L][N] packed bf16x2
    int N, Scales sc)
{
    const int lvl = blockIdx.x & 7;
    const int i = (blockIdx.x >> 3) * blockDim.x + threadIdx.x;
    if (i >= N) return;

    float xx = __builtin_nontemporal_load(x + 3 * i + 0);
    float yy = __builtin_nontemporal_load(x + 3 * i + 1);
    float zz = __builtin_nontemporal_load(x + 3 * i + 2);
    float px = (xx + 1.0f) * 0.5f;
    float py = (yy + 1.0f) * 0.5f;
    float pz = (zz + 1.0f) * 0.5f;

    const float s = sc.s[lvl];
    float fx = fmaf(px, s, 0.5f);
    float fy = fmaf(py, s, 0.5f);
    float fz = fmaf(pz, s, 0.5f);
    float bx = floorf(fx), by = floorf(fy), bz = floorf(fz);
    float wx = fx - bx, wy = fy - by, wz = fz - bz;
    unsigned cx = (unsigned)bx, cy = (unsigned)by, cz = (unsigned)bz;

    unsigned hy0 = cy * 2654435761u;
    unsigned hy1 = hy0 + 2654435761u;
    unsigned hz0 = cz * 805459861u;
    unsigned hz1 = hz0 + 805459861u;
    unsigned cx1 = cx + 1u;
    const unsigned m = TSZ - 1u;
    const f32x2* tl = reinterpret_cast<const f32x2*>(table) + (size_t)lvl * TSZ;

    f32x2 f000 = tl[(cx  ^ hy0 ^ hz0) & m];
    f32x2 f100 = tl[(cx1 ^ hy0 ^ hz0) & m];
    f32x2 f010 = tl[(cx  ^ hy1 ^ hz0) & m];
    f32x2 f110 = tl[(cx1 ^ hy1 ^ hz0) & m];
    f32x2 f001 = tl[(cx  ^ hy0 ^ hz1) & m];
    f32x2 f101 = tl[(cx1 ^ hy0 ^ hz1) & m];
    f32x2 f011 = tl[(cx  ^ hy1 ^ hz1) & m];
    f32x2 f111 = tl[(cx1 ^ hy1 ^ hz1) & m];

    float wx0 = 1.0f - wx, wy0 = 1.0f - wy, wz0 = 1.0f - wz;
    float w00 = wx0 * wy0, w10 = wx * wy0, w01 = wx0 * wy, w11 = wx * wy;
    float a000 = w00 * wz0, a100 = w10 * wz0, a010 = w01 * wz0, a110 = w11 * wz0;
    float a001 = w00 * wz,  a101 = w10 * wz,  a011 = w01 * wz,  a111 = w11 * wz;

    float e0 = fmaf(f000.x, a000,
               fmaf(f100.x, a100,
               fmaf(f010.x, a010,
               fmaf(f110.x, a110,
               fmaf(f001.x, a001,
               fmaf(f101.x, a101,
               fmaf(f011.x, a011, f111.x * a111)))))));
    float e1 = fmaf(f000.y, a000,
               fmaf(f100.y, a100,
               fmaf(f010.y, a010,
               fmaf(f110.y, a110,
               fmaf(f001.y, a001,
               fmaf(f101.y, a101,
               fmaf(f011.y, a011, f111.y * a111)))))));

    unsigned pk = ((unsigned)f2bf(e1) << 16) | (unsigned)f2bf(e0);
    __builtin_nontemporal_store(pk, encb + (size_t)lvl * N + i);
}

// ---------------- MLP pass: 16 -> 32 relu -> 1 sigmoid ----------------
__global__ __launch_bounds__(256) void mlp_kernel(
    const unsigned* __restrict__ encb,  // [L][N] packed bf16x2
    const float* __restrict__ W1,       // [16,32]
    const float* __restrict__ b1,       // [32]
    const float* __restrict__ W2,       // [32]
    const float* __restrict__ b2,       // [1]
    float* __restrict__ out, int N)
{
    int i = blockIdx.x * blockDim.x + threadIdx.x;
    if (i >= N) return;

    float enc[16];
    #pragma unroll
    for (int l = 0; l < NLVL; ++l) {
        unsigned pk = __builtin_nontemporal_load(encb + (size_t)l * N + i);
        enc[2 * l + 0] = bfbits2f(pk << 16);
        enc[2 * l + 1] = bfbits2f(pk & 0xffff0000u);
    }

    float h[32];
    #pragma unroll
    for (int j = 0; j < 32; ++j) h[j] = b1[j];
    #pragma unroll
    for (int k = 0; k < 16; ++k) {
        float e = enc[k];
        #pragma unroll
        for (int j = 0; j < 32; ++j)
            h[j] = fmaf(e, W1[k * 32 + j], h[j]);
    }
    float z = b2[0];
    #pragma unroll
    for (int j = 0; j < 32; ++j)
        z = fmaf(fmaxf(h[j], 0.0f), W2[j], z);

    out[i] = 1.0f / (1.0f + __expf(-z));
}

// ---------------- Fallback: fully fused (ws too small) ----------------
__global__ __launch_bounds__(256) void fused_kernel(
    const float* __restrict__ x, const float* __restrict__ table,
    const float* __restrict__ W1, const float* __restrict__ b1,
    const float* __restrict__ W2, const float* __restrict__ b2,
    float* __restrict__ out, int N, Scales sc)
{
    int i = blockIdx.x * blockDim.x + threadIdx.x;
    if (i >= N) return;
    float px = (x[3 * i + 0] + 1.0f) * 0.5f;
    float py = (x[3 * i + 1] + 1.0f) * 0.5f;
    float pz = (x[3 * i + 2] + 1.0f) * 0.5f;
    float enc[16];
    #pragma unroll
    for (int l = 0; l < NLVL; ++l) {
        const float s = sc.s[l];
        float fx = fmaf(px, s, 0.5f), fy = fmaf(py, s, 0.5f), fz = fmaf(pz, s, 0.5f);
        float bx = floorf(fx), by = floorf(fy), bz = floorf(fz);
        float wx = fx - bx, wy = fy - by, wz = fz - bz;
        unsigned cx = (unsigned)bx, cy = (unsigned)by, cz = (unsigned)bz;
        unsigned hy0 = cy * 2654435761u, hy1 = hy0 + 2654435761u;
        unsigned hz0 = cz * 805459861u, hz1 = hz0 + 805459861u;
        unsigned cx1 = cx + 1u;
        const unsigned m = TSZ - 1u;
        const f32x2* tl = reinterpret_cast<const f32x2*>(table) + (size_t)l * TSZ;
        f32x2 f000 = tl[(cx ^ hy0 ^ hz0) & m], f100 = tl[(cx1 ^ hy0 ^ hz0) & m];
        f32x2 f010 = tl[(cx ^ hy1 ^ hz0) & m], f110 = tl[(cx1 ^ hy1 ^ hz0) & m];
        f32x2 f001 = tl[(cx ^ hy0 ^ hz1) & m], f101 = tl[(cx1 ^ hy0 ^ hz1) & m];
        f32x2 f011 = tl[(cx ^ hy1 ^ hz1) & m], f111 = tl[(cx1 ^ hy1 ^ hz1) & m];
        float wx0 = 1.0f - wx, wy0 = 1.0f - wy, wz0 = 1.0f - wz;
        float w00 = wx0 * wy0, w10 = wx * wy0, w01 = wx0 * wy, w11 = wx * wy;
        float a000 = w00 * wz0, a100 = w10 * wz0, a010 = w01 * wz0, a110 = w11 * wz0;
        float a001 = w00 * wz, a101 = w10 * wz, a011 = w01 * wz, a111 = w11 * wz;
        enc[2*l+0] = fmaf(f000.x,a000, fmaf(f100.x,a100, fmaf(f010.x,a010, fmaf(f110.x,a110,
                     fmaf(f001.x,a001, fmaf(f101.x,a101, fmaf(f011.x,a011, f111.x*a111)))))));
        enc[2*l+1] = fmaf(f000.y,a000, fmaf(f100.y,a100, fmaf(f010.y,a010, fmaf(f110.y,a110,
                     fmaf(f001.y,a001, fmaf(f101.y,a101, fmaf(f011.y,a011, f111.y*a111)))))));
    }
    float h[32];
    #pragma unroll
    for (int j = 0; j < 32; ++j) h[j] = b1[j];
    #pragma unroll
    for (int k = 0; k < 16; ++k) {
        float e = enc[k];
        #pragma unroll
        for (int j = 0; j < 32; ++j) h[j] = fmaf(e, W1[k * 32 + j], h[j]);
    }
    float z = b2[0];
    #pragma unroll
    for (int j = 0; j < 32; ++j) z = fmaf(fmaxf(h[j], 0.0f), W2[j], z);
    out[i] = 1.0f / (1.0f + __expf(-z));
}

extern "C" void kernel_launch(void* const* d_in, const int* in_sizes, int n_in,
                              void* d_out, int out_size, void* d_ws, size_t ws_size,
                              hipStream_t stream) {
    const float* x     = (const float*)d_in[0];
    const float* table = (const float*)d_in[1];
    const float* W1    = (const float*)d_in[2];
    const float* b1    = (const float*)d_in[3];
    const float* W2    = (const float*)d_in[4];
    const float* b2    = (const float*)d_in[5];
    float* out = (float*)d_out;

    int N = in_sizes[0] / 3;

    Scales sc;
    double B = exp(log(2048.0 / 32.0) / 7.0);
    for (int l = 0; l < NLVL; ++l)
        sc.s[l] = (float)(32.0 * pow(B, (double)l) - 1.0);

    const int block = 256;
    const int chunks = (N + block - 1) / block;
    size_t need = (size_t)NLVL * (size_t)N * sizeof(unsigned);

    if (ws_size >= need) {
        unsigned* encb = (unsigned*)d_ws;
        encode_kernel<<<chunks * NLVL, block, 0, stream>>>(x, table, encb, N, sc);
        mlp_kernel<<<chunks, block, 0, stream>>>(encb, W1, b1, W2, b2, out, N);
    } else {
        fused_kernel<<<chunks, block, 0, stream>>>(x, table, W1, b1, W2, b2, out, N, sc);
    }
}